// Round 4
// baseline (882.182 us; speedup 1.0000x reference)
//
#include <hip/hip_runtime.h>
#include <stdint.h>

typedef unsigned int u32;
typedef unsigned short u16;

#define OUT_LATENT (2048*1024)
#define SCALE 0.08838834764831845f  // 1/sqrt(128)

typedef float f32x4v __attribute__((ext_vector_type(4)));
typedef short s16x8  __attribute__((ext_vector_type(8)));

// ticket ranges: [0,64) qk | [64,2112) conv | then 16 groups x 160:
//   per group g: 128 attn patches, 16 ctx tiles, 16 out tiles
#define T_CONV0 64
#define T_G0    2112
#define T_END   4672
// counters (u32, zeroed by hipMemsetAsync): [0] ticket, [1] c_qk, [2] c_wv,
// [3] c_ow, [4..19] c_attn[g], [20..35] c_ctx[g]

static __device__ inline u16 f2bf(float f) {
    union { float f; uint32_t u; } v; v.f = f;
    uint32_t u = v.u;
    return (u16)((u + 0x7FFFu + ((u >> 16) & 1u)) >> 16); // RNE
}
static __device__ inline float bflo(uint32_t u) {
    union { uint32_t u; float f; } v; v.u = u << 16; return v.f;
}
static __device__ inline float bfhi(uint32_t u) {
    union { uint32_t u; float f; } v; v.u = u & 0xFFFF0000u; return v.f;
}
static __device__ __forceinline__ void async16(const u16* g, u16* l) {
    __builtin_amdgcn_global_load_lds(
        (const __attribute__((address_space(1))) void*)g,
        (__attribute__((address_space(3))) void*)l, 16, 0, 0);
}

union SMem {
    struct { u16 tokL[16][1032]; float scoresP[4][16][8]; float attnL[16][8]; int allz; } a;
    struct { u16 As[128 * 32]; u16 Bs[64 * 32]; } g;
    struct { float qs[128]; float part[128]; } q;
};

// ---- inter-block sync (device scope, acquire/release) ----------------------
static __device__ __forceinline__ void wait_ge(u32* p, u32 need) {
    if (threadIdx.x == 0) {
        while (__hip_atomic_load(p, __ATOMIC_RELAXED, __HIP_MEMORY_SCOPE_AGENT) < need)
            __builtin_amdgcn_s_sleep(32);
        (void)__hip_atomic_load(p, __ATOMIC_ACQUIRE, __HIP_MEMORY_SCOPE_AGENT);
    }
    __syncthreads();
}
static __device__ __forceinline__ void done_add(u32* p) {
    __syncthreads();   // all threads' stores drained (vmcnt(0) before s_barrier)
    if (threadIdx.x == 0)
        (void)__hip_atomic_fetch_add(p, 1u, __ATOMIC_RELEASE, __HIP_MEMORY_SCOPE_AGENT);
}

// ---- role: qk precompute (64 tickets) --------------------------------------
static __device__ void role_qk(SMem& sm, int tk,
    const float* __restrict__ ipw, const float* __restrict__ ipb,
    const float* __restrict__ pq, u16* __restrict__ qkb, float* __restrict__ sb,
    u32* ctr) {
    int h = tk >> 3, jseg = tk & 7, t = threadIdx.x;
    // q segment for this head: thread pair (dl = t>>1, half = t&1)
    {
        int dl = t >> 1, half = t & 1;
        const float* wrow = ipw + (size_t)(h * 128 + dl) * 1024 + half * 512;
        const float* pqh = pq + half * 512;
        float a = 0.f;
        #pragma unroll 8
        for (int j = 0; j < 512; j += 4) {
            float4 w = *(const float4*)(wrow + j);
            float4 p = *(const float4*)(pqh + j);
            a = fmaf(w.x, p.x, a); a = fmaf(w.y, p.y, a);
            a = fmaf(w.z, p.z, a); a = fmaf(w.w, p.w, a);
        }
        a += __shfl_xor(a, 1);
        if (!half) sm.q.qs[dl] = a + ipb[h * 128 + dl];
    }
    __syncthreads();
    int jl = t & 127, dh = t >> 7;
    float acc = 0.f;
    const float* wbase = ipw + (size_t)(1024 + h * 128 + dh * 64) * 1024 + jseg * 128 + jl;
    #pragma unroll 8
    for (int d = 0; d < 64; ++d)
        acc = fmaf(sm.q.qs[dh * 64 + d], wbase[(size_t)d * 1024], acc);
    if (dh) sm.q.part[jl] = acc;
    __syncthreads();
    if (!dh) qkb[h * 1024 + jseg * 128 + jl] = f2bf((acc + sm.q.part[jl]) * SCALE);
    if (jseg == 0 && t < 64) {
        const float* bk = ipb + 1024 + h * 128;
        float p = sm.q.qs[t] * bk[t] + sm.q.qs[t + 64] * bk[t + 64];
        #pragma unroll
        for (int m = 32; m >= 1; m >>= 1) p += __shfl_xor(p, m);
        if (t == 0) sb[h] = p * SCALE;
    }
    done_add(ctr + 1);
}

// ---- role: weight conversion (2048 tickets) --------------------------------
static __device__ void role_conv(int b,
    const float* __restrict__ ipw, const float* __restrict__ ow,
    u16* __restrict__ wv_dst, u16* __restrict__ ow_dst, u32* ctr) {
    int t = threadIdx.x;
    const float* src; u16* dst; int idx;
    if (b < 1024) { src = ipw + (size_t)2048 * 1024; dst = wv_dst; idx = b * 1024 + t * 4; }
    else          { src = ow;                        dst = ow_dst; idx = (b - 1024) * 1024 + t * 4; }
    float4 f = *(const float4*)(src + idx);
    ushort4 o; o.x = f2bf(f.x); o.y = f2bf(f.y); o.z = f2bf(f.z); o.w = f2bf(f.w);
    *(ushort4*)(dst + idx) = o;
    done_add(ctr + (b < 1024 ? 2 : 3));
}

// ---- role: fused gather + MFMA scores + softmax + mix (2048 tickets) -------
static __device__ void role_attn(SMem& sm, int bp,
    const int* __restrict__ tok_ids, const int* __restrict__ amask,
    const float* __restrict__ emb, const u16* __restrict__ qkb,
    const float* __restrict__ sb, u16* __restrict__ Mout,
    float* __restrict__ pv, u32* ctr) {
    int t = threadIdx.x;
    int wave = t >> 6, lane = t & 63, lrow = lane & 15, quad = lane >> 4;

    // B-frag prefetch for scores MFMA: wave w covers k in [w*256, +256)
    s16x8 bfr[8];
    {
        const u16* qbase = qkb + (lane & 7) * 1024 + wave * 256 + quad * 8;
        #pragma unroll
        for (int s = 0; s < 8; ++s) bfr[s] = *(const s16x8*)(qbase + s * 32);
    }
    // gather 16 embedding rows -> LDS bf16
    {
        int row = t >> 4, c = t & 15;
        int tid = tok_ids[bp * 16 + row];
        const float* erow = emb + (size_t)tid * 1024;
        #pragma unroll
        for (int i = 0; i < 16; ++i) {
            int j4 = c + i * 16;
            float4 f = *(const float4*)(erow + j4 * 4);
            ushort4 o; o.x = f2bf(f.x); o.y = f2bf(f.y); o.z = f2bf(f.z); o.w = f2bf(f.w);
            *(ushort4*)(&sm.a.tokL[row][j4 * 4]) = o;
        }
    }
    if (t < 16) {
        int any = (amask[bp * 16 + t] != 0);
        any |= __shfl_xor(any, 1); any |= __shfl_xor(any, 2);
        any |= __shfl_xor(any, 4); any |= __shfl_xor(any, 8);
        if (t == 0) { pv[bp] = any ? 1.f : 0.f; sm.a.allz = any ? 0 : 1; }
    }
    __syncthreads();

    // scores via MFMA: D[l][h] partial over this wave's k-range
    {
        f32x4v acc = (f32x4v){0.f, 0.f, 0.f, 0.f};
        const u16* arow = &sm.a.tokL[lrow][wave * 256 + quad * 8];
        #pragma unroll
        for (int s = 0; s < 8; ++s) {
            s16x8 af = *(const s16x8*)(arow + s * 32);
            acc = __builtin_amdgcn_mfma_f32_16x16x32_bf16(af, bfr[s], acc, 0, 0, 0);
        }
        if (lrow < 8) {
            #pragma unroll
            for (int r = 0; r < 4; ++r) sm.a.scoresP[wave][quad * 4 + r][lrow] = acc[r];
        }
    }
    __syncthreads();

    // masked softmax over l per head
    if (t < 128) {
        int hh = t >> 4, ll = t & 15;
        float s = sm.a.scoresP[0][ll][hh] + sm.a.scoresP[1][ll][hh]
                + sm.a.scoresP[2][ll][hh] + sm.a.scoresP[3][ll][hh] + sb[hh];
        bool valid = (amask[bp * 16 + ll] != 0) || (sm.a.allz && ll == 0);
        s = valid ? s : -1e30f;
        float mx = s;
        mx = fmaxf(mx, __shfl_xor(mx, 1)); mx = fmaxf(mx, __shfl_xor(mx, 2));
        mx = fmaxf(mx, __shfl_xor(mx, 4)); mx = fmaxf(mx, __shfl_xor(mx, 8));
        float e = __expf(s - mx);
        float sum = e;
        sum += __shfl_xor(sum, 1); sum += __shfl_xor(sum, 2);
        sum += __shfl_xor(sum, 4); sum += __shfl_xor(sum, 8);
        sm.a.attnL[ll][hh] = e / sum;
    }
    __syncthreads();

    // mix: m[h][j] = sum_l attn[h][l] * tok[l][j]; thread owns 4 j's
    float macc[8][4];
    #pragma unroll
    for (int h = 0; h < 8; ++h)
        #pragma unroll
        for (int c = 0; c < 4; ++c) macc[h][c] = 0.f;
    #pragma unroll
    for (int ll = 0; ll < 16; ++ll) {
        uint2 tv = *(const uint2*)(&sm.a.tokL[ll][t * 4]);
        float t0 = bflo(tv.x), t1 = bfhi(tv.x), t2 = bflo(tv.y), t3 = bfhi(tv.y);
        float4 a0 = *(const float4*)(&sm.a.attnL[ll][0]);
        float4 a1 = *(const float4*)(&sm.a.attnL[ll][4]);
        macc[0][0] = fmaf(a0.x, t0, macc[0][0]); macc[0][1] = fmaf(a0.x, t1, macc[0][1]);
        macc[0][2] = fmaf(a0.x, t2, macc[0][2]); macc[0][3] = fmaf(a0.x, t3, macc[0][3]);
        macc[1][0] = fmaf(a0.y, t0, macc[1][0]); macc[1][1] = fmaf(a0.y, t1, macc[1][1]);
        macc[1][2] = fmaf(a0.y, t2, macc[1][2]); macc[1][3] = fmaf(a0.y, t3, macc[1][3]);
        macc[2][0] = fmaf(a0.z, t0, macc[2][0]); macc[2][1] = fmaf(a0.z, t1, macc[2][1]);
        macc[2][2] = fmaf(a0.z, t2, macc[2][2]); macc[2][3] = fmaf(a0.z, t3, macc[2][3]);
        macc[3][0] = fmaf(a0.w, t0, macc[3][0]); macc[3][1] = fmaf(a0.w, t1, macc[3][1]);
        macc[3][2] = fmaf(a0.w, t2, macc[3][2]); macc[3][3] = fmaf(a0.w, t3, macc[3][3]);
        macc[4][0] = fmaf(a1.x, t0, macc[4][0]); macc[4][1] = fmaf(a1.x, t1, macc[4][1]);
        macc[4][2] = fmaf(a1.x, t2, macc[4][2]); macc[4][3] = fmaf(a1.x, t3, macc[4][3]);
        macc[5][0] = fmaf(a1.y, t0, macc[5][0]); macc[5][1] = fmaf(a1.y, t1, macc[5][1]);
        macc[5][2] = fmaf(a1.y, t2, macc[5][2]); macc[5][3] = fmaf(a1.y, t3, macc[5][3]);
        macc[6][0] = fmaf(a1.z, t0, macc[6][0]); macc[6][1] = fmaf(a1.z, t1, macc[6][1]);
        macc[6][2] = fmaf(a1.z, t2, macc[6][2]); macc[6][3] = fmaf(a1.z, t3, macc[6][3]);
        macc[7][0] = fmaf(a1.w, t0, macc[7][0]); macc[7][1] = fmaf(a1.w, t1, macc[7][1]);
        macc[7][2] = fmaf(a1.w, t2, macc[7][2]); macc[7][3] = fmaf(a1.w, t3, macc[7][3]);
    }
    #pragma unroll
    for (int h = 0; h < 8; ++h) {
        ushort4 o;
        o.x = f2bf(macc[h][0]); o.y = f2bf(macc[h][1]);
        o.z = f2bf(macc[h][2]); o.w = f2bf(macc[h][3]);
        *(ushort4*)(Mout + ((size_t)(h * 2048 + bp)) * 1024 + t * 4) = o;
    }
    done_add(ctr + 4 + (bp >> 7));
}

// ---- 128x64x1024 NT bf16 MFMA tile (R2-proven staging structure) -----------
static __device__ __forceinline__ void gemm_tile_128x64(
    const u16* __restrict__ A, const u16* __restrict__ B, SMem& sm,
    f32x4v acc[4][2]) {
    int t = threadIdx.x;
    int wave = t >> 6, lane = t & 63, lrow = lane & 15, quad = lane >> 4;
    int wm = wave & 1, wn = wave >> 1;
    int r4 = t >> 2, seg = (t & 3) * 8;
    u16* As = sm.g.As; u16* Bs = sm.g.Bs;
    #pragma unroll
    for (int mi = 0; mi < 4; ++mi)
        #pragma unroll
        for (int ni = 0; ni < 2; ++ni) acc[mi][ni] = (f32x4v){0.f, 0.f, 0.f, 0.f};
    for (int step = 0; step < 32; ++step) {
        int k0 = step * 32;
        __syncthreads();
        async16(A + (size_t)r4 * 1024 + k0 + seg,        As + t * 8);
        async16(A + (size_t)(r4 + 64) * 1024 + k0 + seg, As + (256 + t) * 8);
        async16(B + (size_t)r4 * 1024 + k0 + seg,        Bs + t * 8);
        __syncthreads();
        s16x8 af[4], bf[2];
        #pragma unroll
        for (int mi = 0; mi < 4; ++mi)
            af[mi] = *(const s16x8*)(As + (wm * 64 + mi * 16 + lrow) * 32 + quad * 8);
        #pragma unroll
        for (int ni = 0; ni < 2; ++ni)
            bf[ni] = *(const s16x8*)(Bs + (wn * 32 + ni * 16 + lrow) * 32 + quad * 8);
        #pragma unroll
        for (int mi = 0; mi < 4; ++mi)
            #pragma unroll
            for (int ni = 0; ni < 2; ++ni)
                acc[mi][ni] = __builtin_amdgcn_mfma_f32_16x16x32_bf16(af[mi], bf[ni], acc[mi][ni], 0, 0, 0);
    }
}

// ---- role: ctx tile (16 groups x 16 tiles) ---------------------------------
static __device__ void role_ctx(SMem& sm, int mb, int cn,
    const u16* __restrict__ M, const u16* __restrict__ wv,
    const float* __restrict__ ipb, u16* __restrict__ ctx, u32* ctr) {
    int h = cn >> 1;
    f32x4v acc[4][2];
    gemm_tile_128x64(M + ((size_t)h * 2048 + mb * 128) * 1024,
                     wv + (size_t)cn * 64 * 1024, sm, acc);
    int t = threadIdx.x, wave = t >> 6, lane = t & 63, lrow = lane & 15, quad = lane >> 4;
    int wm = wave & 1, wn = wave >> 1;
    #pragma unroll
    for (int ni = 0; ni < 2; ++ni) {
        int n_g = cn * 64 + wn * 32 + ni * 16 + lrow;
        float bias = ipb[2048 + n_g];
        #pragma unroll
        for (int mi = 0; mi < 4; ++mi) {
            #pragma unroll
            for (int r = 0; r < 4; ++r) {
                int m_g = mb * 128 + wm * 64 + mi * 16 + quad * 4 + r;
                ctx[(size_t)m_g * 1024 + n_g] = f2bf(acc[mi][ni][r] + bias);
            }
        }
    }
    done_add(ctr + 20 + mb);
}

// ---- role: out tile (16 groups x 16 tiles) ---------------------------------
static __device__ void role_out(SMem& sm, int mb, int nt,
    const u16* __restrict__ ctx, const u16* __restrict__ ow,
    const float* __restrict__ outb, const float* __restrict__ pv,
    float* __restrict__ out) {
    f32x4v acc[4][2];
    gemm_tile_128x64(ctx + (size_t)mb * 128 * 1024,
                     ow + (size_t)nt * 64 * 1024, sm, acc);
    int t = threadIdx.x, wave = t >> 6, lane = t & 63, lrow = lane & 15, quad = lane >> 4;
    int wm = wave & 1, wn = wave >> 1;
    #pragma unroll
    for (int ni = 0; ni < 2; ++ni) {
        int n_g = nt * 64 + wn * 32 + ni * 16 + lrow;
        float bias = outb[n_g];
        #pragma unroll
        for (int mi = 0; mi < 4; ++mi) {
            #pragma unroll
            for (int r = 0; r < 4; ++r) {
                int m_g = mb * 128 + wm * 64 + mi * 16 + quad * 4 + r;
                out[(size_t)m_g * 1024 + n_g] = (acc[mi][ni][r] + bias) * pv[m_g];
            }
        }
    }
    if (nt == 0 && t < 128) out[OUT_LATENT + mb * 128 + t] = pv[mb * 128 + t];
}

// ---- persistent mega-kernel ------------------------------------------------
__global__ __launch_bounds__(256, 4) void k_mega(
    const int* __restrict__ tok, const int* __restrict__ msk,
    const float* __restrict__ emb, const float* __restrict__ pq,
    const float* __restrict__ ipw, const float* __restrict__ ipb,
    const float* __restrict__ ow, const float* __restrict__ ob,
    float* __restrict__ out, u32* ctr, float* sb, float* pv,
    u16* qkb, u16* wv_b, u16* ow_b, u16* ctx_b, u16* M_b) {
    __shared__ SMem sm;
    __shared__ u32 tkS;
    bool qk_ok = false, wv_ok = false, ow_ok = false;
    for (;;) {
        __syncthreads();
        if (threadIdx.x == 0)
            tkS = __hip_atomic_fetch_add(ctr, 1u, __ATOMIC_RELAXED, __HIP_MEMORY_SCOPE_AGENT);
        __syncthreads();
        u32 tk = tkS;
        if (tk >= T_END) return;
        if (tk < T_CONV0) {
            role_qk(sm, tk, ipw, ipb, pq, qkb, sb, ctr);
        } else if (tk < T_G0) {
            role_conv(tk - T_CONV0, ipw, ow, wv_b, ow_b, ctr);
        } else {
            u32 r = tk - T_G0;
            u32 g = r / 160u, o = r % 160u;
            if (o < 128) {
                if (!qk_ok) { wait_ge(ctr + 1, 64); qk_ok = true; }
                role_attn(sm, g * 128 + o, tok, msk, emb, qkb, sb, M_b, pv, ctr);
            } else if (o < 144) {
                if (!wv_ok) { wait_ge(ctr + 2, 1024); wv_ok = true; }
                wait_ge(ctr + 4 + g, 128);
                role_ctx(sm, g, o - 128, M_b, wv_b, ipb, ctx_b, ctr);
            } else {
                if (!ow_ok) { wait_ge(ctr + 3, 1024); ow_ok = true; }
                wait_ge(ctr + 20 + g, 16);
                role_out(sm, g, o - 144, ctx_b, ow_b, ob, pv, out);
            }
        }
    }
}

// ---------------------------------------------------------------------------
extern "C" void kernel_launch(void* const* d_in, const int* in_sizes, int n_in,
                              void* d_out, int out_size, void* d_ws, size_t ws_size,
                              hipStream_t stream) {
    const int*   tok = (const int*)d_in[0];
    const int*   msk = (const int*)d_in[1];
    const float* emb = (const float*)d_in[2];
    const float* pq  = (const float*)d_in[3];
    const float* ipw = (const float*)d_in[4];
    const float* ipb = (const float*)d_in[5];
    const float* ow  = (const float*)d_in[6];
    const float* ob  = (const float*)d_in[7];
    float* out = (float*)d_out;
    char* ws = (char*)d_ws;

    u32*   ctr   = (u32*)(ws + 0);                         // 256 B (zeroed below)
    float* sb_f  = (float*)(ws + 4096);                    // 32 B
    float* pv_f  = (float*)(ws + 8192);                    // 8 KB
    u16*   qk_b  = (u16*)(ws + 16384);                     // 16 KB
    u16*   wv_b  = (u16*)(ws + 32768);                     // 2 MB
    u16*   ow_b  = (u16*)(ws + 32768 + 2097152);           // 2 MB
    u16*   ctx_b = (u16*)(ws + 32768 + 2 * 2097152);       // 4 MB
    u16*   M_b   = (u16*)(ws + 32768 + 2 * 2097152 + 4194304); // 32 MB

    hipMemsetAsync(ws, 0, 256, stream);
    k_mega<<<dim3(1024), dim3(256), 0, stream>>>(
        tok, msk, emb, pq, ipw, ipb, ow, ob, out,
        ctr, sb_f, pv_f, qk_b, wv_b, ow_b, ctx_b, M_b);
}

// Round 5
// 299.112 us; speedup vs baseline: 2.9493x; 2.9493x over previous
//
#include <hip/hip_runtime.h>
#include <stdint.h>

typedef unsigned short u16;

#define OUT_LATENT (2048*1024)
#define SCALE 0.08838834764831845f  // 1/sqrt(128)

typedef float f32x4v __attribute__((ext_vector_type(4)));
typedef short s16x8  __attribute__((ext_vector_type(8)));

static __device__ inline u16 f2bf(float f) {
    union { float f; uint32_t u; } v; v.f = f;
    uint32_t u = v.u;
    return (u16)((u + 0x7FFFu + ((u >> 16) & 1u)) >> 16); // RNE
}
static __device__ inline float bflo(uint32_t u) {
    union { uint32_t u; float f; } v; v.u = u << 16; return v.f;
}
static __device__ inline float bfhi(uint32_t u) {
    union { uint32_t u; float f; } v; v.u = u & 0xFFFF0000u; return v.f;
}
static __device__ __forceinline__ void async16(const u16* g, u16* l) {
    __builtin_amdgcn_global_load_lds(
        (const __attribute__((address_space(1))) void*)g,
        (__attribute__((address_space(3))) void*)l, 16, 0, 0);
}

// ---------------------------------------------------------------------------
// Kernel 1 (fused prep): blocks [0,2048) convert wv/out_w to bf16;
// blocks [2048,2112) compute qk[h][j] = SCALE*sum_d q[h*128+d]*wk[h*128+d][j],
// q recomputed per block (q = pq . wq^T + bq); sb[h] = SCALE*q_h.bk_h.
__global__ __launch_bounds__(256) void k_prep(
    const float* __restrict__ ipw, const float* __restrict__ ipb,
    const float* __restrict__ pq, const float* __restrict__ ow,
    u16* __restrict__ wv_dst, u16* __restrict__ ow_dst,
    u16* __restrict__ qkb, float* __restrict__ sb) {
    __shared__ float qs[128];
    __shared__ float part[128];
    int t = threadIdx.x, b = blockIdx.x;

    if (b < 2048) {  // --- weight conversion ---
        const float* src; u16* dst; int idx;
        if (b < 1024) { src = ipw + (size_t)2048 * 1024; dst = wv_dst; idx = b * 1024 + t * 4; }
        else          { src = ow;                        dst = ow_dst; idx = (b - 1024) * 1024 + t * 4; }
        float4 f = *(const float4*)(src + idx);
        ushort4 o; o.x = f2bf(f.x); o.y = f2bf(f.y); o.z = f2bf(f.z); o.w = f2bf(f.w);
        *(ushort4*)(dst + idx) = o;
        return;
    }

    int bb = b - 2048;
    int h = bb >> 3, jseg = bb & 7;
    {
        int dl = t >> 1, half = t & 1;
        const float* wrow = ipw + (size_t)(h * 128 + dl) * 1024 + half * 512;
        const float* pqh = pq + half * 512;
        float a = 0.f;
        #pragma unroll 8
        for (int j = 0; j < 512; j += 4) {
            float4 w = *(const float4*)(wrow + j);
            float4 p = *(const float4*)(pqh + j);
            a = fmaf(w.x, p.x, a); a = fmaf(w.y, p.y, a);
            a = fmaf(w.z, p.z, a); a = fmaf(w.w, p.w, a);
        }
        a += __shfl_xor(a, 1);
        if (!half) qs[dl] = a + ipb[h * 128 + dl];
    }
    __syncthreads();
    int jl = t & 127, dh = t >> 7;
    float acc = 0.f;
    const float* wbase = ipw + (size_t)(1024 + h * 128 + dh * 64) * 1024 + jseg * 128 + jl;
    #pragma unroll 8
    for (int d = 0; d < 64; ++d)
        acc = fmaf(qs[dh * 64 + d], wbase[(size_t)d * 1024], acc);
    if (dh) part[jl] = acc;
    __syncthreads();
    if (!dh) qkb[h * 1024 + jseg * 128 + jl] = f2bf((acc + part[jl]) * SCALE);
    if (jseg == 0 && t < 64) {
        const float* bk = ipb + 1024 + h * 128;
        float p = qs[t] * bk[t] + qs[t + 64] * bk[t + 64];
        #pragma unroll
        for (int m = 32; m >= 1; m >>= 1) p += __shfl_xor(p, m);
        if (t == 0) sb[h] = p * SCALE;
    }
}

// ---------------------------------------------------------------------------
// Kernel 2: per-patch fused gather + MFMA scores + softmax + attention mix.
// grid 2048 x 256.  Outputs M[h][bp][j] (bf16) and pv[bp] (f32 0/1).
__global__ __launch_bounds__(256) void k_attn(
    const int* __restrict__ tok_ids, const int* __restrict__ amask,
    const float* __restrict__ emb, const u16* __restrict__ qkb,
    const float* __restrict__ sb, u16* __restrict__ Mout,
    float* __restrict__ pv) {
    __shared__ u16 tokL[16][1032];       // +8 pad: row stride 2064 B
    __shared__ float scoresP[4][16][8];
    __shared__ float attnL[16][8];
    __shared__ int allzL;

    int bp = blockIdx.x, t = threadIdx.x;
    int wave = t >> 6, lane = t & 63, lrow = lane & 15, quad = lane >> 4;

    // patch-valid flag first (cheap, independent)
    if (t < 16) {
        int any = (amask[bp * 16 + t] != 0);
        any |= __shfl_xor(any, 1); any |= __shfl_xor(any, 2);
        any |= __shfl_xor(any, 4); any |= __shfl_xor(any, 8);
        if (t == 0) { pv[bp] = any ? 1.f : 0.f; allzL = any ? 0 : 1; }
    }

    // gather 16 embedding rows -> LDS bf16, batched 8-deep for MLP
    int row = t >> 4, c = t & 15;
    int tid = tok_ids[bp * 16 + row];
    const float* erow = emb + (size_t)tid * 1024;
    float4 ld[8];
    #pragma unroll
    for (int i = 0; i < 8; ++i) ld[i] = *(const float4*)(erow + (c + i * 16) * 4);

    // B-frag prefetch for scores MFMA (overlaps with converts below)
    s16x8 bfr[8];
    {
        const u16* qbase = qkb + (lane & 7) * 1024 + wave * 256 + quad * 8;
        #pragma unroll
        for (int s = 0; s < 8; ++s) bfr[s] = *(const s16x8*)(qbase + s * 32);
    }
    #pragma unroll
    for (int i = 0; i < 8; ++i) {
        ushort4 o; o.x = f2bf(ld[i].x); o.y = f2bf(ld[i].y);
        o.z = f2bf(ld[i].z); o.w = f2bf(ld[i].w);
        *(ushort4*)(&tokL[row][(c + i * 16) * 4]) = o;
    }
    #pragma unroll
    for (int i = 0; i < 8; ++i) ld[i] = *(const float4*)(erow + (c + (i + 8) * 16) * 4);
    #pragma unroll
    for (int i = 0; i < 8; ++i) {
        ushort4 o; o.x = f2bf(ld[i].x); o.y = f2bf(ld[i].y);
        o.z = f2bf(ld[i].z); o.w = f2bf(ld[i].w);
        *(ushort4*)(&tokL[row][(c + (i + 8) * 16) * 4]) = o;
    }
    __syncthreads();

    // scores via MFMA: D[l][h] partial over this wave's k-range [wave*256,+256)
    {
        f32x4v acc = (f32x4v){0.f, 0.f, 0.f, 0.f};
        const u16* arow = &tokL[lrow][wave * 256 + quad * 8];
        #pragma unroll
        for (int s = 0; s < 8; ++s) {
            s16x8 af = *(const s16x8*)(arow + s * 32);
            acc = __builtin_amdgcn_mfma_f32_16x16x32_bf16(af, bfr[s], acc, 0, 0, 0);
        }
        if (lrow < 8) {
            #pragma unroll
            for (int r = 0; r < 4; ++r) scoresP[wave][quad * 4 + r][lrow] = acc[r];
        }
    }
    __syncthreads();

    // masked softmax over l per head (t<128: hh=t>>4, ll=t&15)
    if (t < 128) {
        int hh = t >> 4, ll = t & 15;
        float s = scoresP[0][ll][hh] + scoresP[1][ll][hh]
                + scoresP[2][ll][hh] + scoresP[3][ll][hh] + sb[hh];
        bool valid = (amask[bp * 16 + ll] != 0) || (allzL && ll == 0);
        s = valid ? s : -1e30f;
        float mx = s;
        mx = fmaxf(mx, __shfl_xor(mx, 1)); mx = fmaxf(mx, __shfl_xor(mx, 2));
        mx = fmaxf(mx, __shfl_xor(mx, 4)); mx = fmaxf(mx, __shfl_xor(mx, 8));
        float e = __expf(s - mx);
        float sum = e;
        sum += __shfl_xor(sum, 1); sum += __shfl_xor(sum, 2);
        sum += __shfl_xor(sum, 4); sum += __shfl_xor(sum, 8);
        attnL[ll][hh] = e / sum;
    }
    __syncthreads();

    // mix: m[h][j] = sum_l attn[h][l] * tok[l][j]; thread owns 4 j's
    float macc[8][4];
    #pragma unroll
    for (int h = 0; h < 8; ++h)
        #pragma unroll
        for (int cc = 0; cc < 4; ++cc) macc[h][cc] = 0.f;
    #pragma unroll
    for (int ll = 0; ll < 16; ++ll) {
        uint2 tv = *(const uint2*)(&tokL[ll][t * 4]);
        float t0 = bflo(tv.x), t1 = bfhi(tv.x), t2 = bflo(tv.y), t3 = bfhi(tv.y);
        float4 a0 = *(const float4*)(&attnL[ll][0]);
        float4 a1 = *(const float4*)(&attnL[ll][4]);
        macc[0][0] = fmaf(a0.x, t0, macc[0][0]); macc[0][1] = fmaf(a0.x, t1, macc[0][1]);
        macc[0][2] = fmaf(a0.x, t2, macc[0][2]); macc[0][3] = fmaf(a0.x, t3, macc[0][3]);
        macc[1][0] = fmaf(a0.y, t0, macc[1][0]); macc[1][1] = fmaf(a0.y, t1, macc[1][1]);
        macc[1][2] = fmaf(a0.y, t2, macc[1][2]); macc[1][3] = fmaf(a0.y, t3, macc[1][3]);
        macc[2][0] = fmaf(a0.z, t0, macc[2][0]); macc[2][1] = fmaf(a0.z, t1, macc[2][1]);
        macc[2][2] = fmaf(a0.z, t2, macc[2][2]); macc[2][3] = fmaf(a0.z, t3, macc[2][3]);
        macc[3][0] = fmaf(a0.w, t0, macc[3][0]); macc[3][1] = fmaf(a0.w, t1, macc[3][1]);
        macc[3][2] = fmaf(a0.w, t2, macc[3][2]); macc[3][3] = fmaf(a0.w, t3, macc[3][3]);
        macc[4][0] = fmaf(a1.x, t0, macc[4][0]); macc[4][1] = fmaf(a1.x, t1, macc[4][1]);
        macc[4][2] = fmaf(a1.x, t2, macc[4][2]); macc[4][3] = fmaf(a1.x, t3, macc[4][3]);
        macc[5][0] = fmaf(a1.y, t0, macc[5][0]); macc[5][1] = fmaf(a1.y, t1, macc[5][1]);
        macc[5][2] = fmaf(a1.y, t2, macc[5][2]); macc[5][3] = fmaf(a1.y, t3, macc[5][3]);
        macc[6][0] = fmaf(a1.z, t0, macc[6][0]); macc[6][1] = fmaf(a1.z, t1, macc[6][1]);
        macc[6][2] = fmaf(a1.z, t2, macc[6][2]); macc[6][3] = fmaf(a1.z, t3, macc[6][3]);
        macc[7][0] = fmaf(a1.w, t0, macc[7][0]); macc[7][1] = fmaf(a1.w, t1, macc[7][1]);
        macc[7][2] = fmaf(a1.w, t2, macc[7][2]); macc[7][3] = fmaf(a1.w, t3, macc[7][3]);
    }
    #pragma unroll
    for (int h = 0; h < 8; ++h) {
        ushort4 o;
        o.x = f2bf(macc[h][0]); o.y = f2bf(macc[h][1]);
        o.z = f2bf(macc[h][2]); o.w = f2bf(macc[h][3]);
        *(ushort4*)(Mout + ((size_t)(h * 2048 + bp)) * 1024 + t * 4) = o;
    }
}

// ---------------------------------------------------------------------------
// 128x128x1024 NT bf16 MFMA mainloop, BK=64 (16 steps), global_load_lds x16.
// LDS layout forced lane-linear by async16 -> XOR-swizzle k-segments per row
// (seg_stored = seg_global ^ (row&7)) so fragment reads are 2-way (free).
__device__ __forceinline__ void gemm128_bk64(
    const u16* __restrict__ A, const u16* __restrict__ B,
    u16* As, u16* Bs, f32x4v acc[4][4]) {
    int t = threadIdx.x;
    int wave = t >> 6, lane = t & 63, lrow = lane & 15, quad = lane >> 4;
    int wm = wave & 1, wn = wave >> 1;
    int tr = t >> 3, tc7 = t & 7;
    #pragma unroll
    for (int mi = 0; mi < 4; ++mi)
        #pragma unroll
        for (int ni = 0; ni < 4; ++ni) acc[mi][ni] = (f32x4v){0.f, 0.f, 0.f, 0.f};
    for (int step = 0; step < 16; ++step) {
        int k0 = step * 64;
        __syncthreads();
        #pragma unroll
        for (int rb = 0; rb < 128; rb += 32) {
            int r = rb + tr;
            int gofs = (tc7 ^ (r & 7)) * 8;          // swizzled k-seg for this slot
            async16(A + (size_t)r * 1024 + k0 + gofs, As + rb * 64 + t * 8);
            async16(B + (size_t)r * 1024 + k0 + gofs, Bs + rb * 64 + t * 8);
        }
        __syncthreads();
        #pragma unroll
        for (int kk = 0; kk < 2; ++kk) {
            s16x8 af[4], bf[4];
            #pragma unroll
            for (int i = 0; i < 4; ++i) {
                int ra = wm * 64 + i * 16 + lrow;
                af[i] = *(const s16x8*)(As + ra * 64 + (((kk * 4 + quad) ^ (ra & 7)) * 8));
                int rb2 = wn * 64 + i * 16 + lrow;
                bf[i] = *(const s16x8*)(Bs + rb2 * 64 + (((kk * 4 + quad) ^ (rb2 & 7)) * 8));
            }
            #pragma unroll
            for (int mi = 0; mi < 4; ++mi)
                #pragma unroll
                for (int ni = 0; ni < 4; ++ni)
                    acc[mi][ni] = __builtin_amdgcn_mfma_f32_16x16x32_bf16(af[mi], bf[ni], acc[mi][ni], 0, 0, 0);
        }
    }
}

// Kernel 3: ctx[bp][h*128+n] = M_h[bp,:] . wv_h[n,:] + bv   grid (16 mb, 8 h)
__global__ __launch_bounds__(256) void k_gemm_ctx(
    const u16* __restrict__ M, const u16* __restrict__ wv,
    const float* __restrict__ ipb, u16* __restrict__ ctx) {
    __shared__ u16 As[128 * 64], Bs[128 * 64];
    int mb = blockIdx.x, h = blockIdx.y;
    f32x4v acc[4][4];
    gemm128_bk64(M + ((size_t)h * 2048 + mb * 128) * 1024,
                 wv + (size_t)h * 128 * 1024, As, Bs, acc);
    int t = threadIdx.x, wave = t >> 6, lane = t & 63, lrow = lane & 15, quad = lane >> 4;
    int wm = wave & 1, wn = wave >> 1;
    #pragma unroll
    for (int ni = 0; ni < 4; ++ni) {
        int n_g = h * 128 + wn * 64 + ni * 16 + lrow;
        float bias = ipb[2048 + n_g];
        #pragma unroll
        for (int mi = 0; mi < 4; ++mi) {
            #pragma unroll
            for (int r = 0; r < 4; ++r) {
                int m_g = mb * 128 + wm * 64 + mi * 16 + quad * 4 + r;
                ctx[(size_t)m_g * 1024 + n_g] = f2bf(acc[mi][ni][r] + bias);
            }
        }
    }
}

// Kernel 4: out[bp][n] = (ctx[bp,:] . out_w[n,:] + out_b[n]) * pv[bp]
// grid (16 mb, 8 nb); nb==0 blocks write the pv tail.
__global__ __launch_bounds__(256) void k_gemm_out(
    const u16* __restrict__ ctx, const u16* __restrict__ ow,
    const float* __restrict__ outb, const float* __restrict__ pv,
    float* __restrict__ out) {
    __shared__ u16 As[128 * 64], Bs[128 * 64];
    int mb = blockIdx.x, nb = blockIdx.y;
    f32x4v acc[4][4];
    gemm128_bk64(ctx + (size_t)mb * 128 * 1024,
                 ow + (size_t)nb * 128 * 1024, As, Bs, acc);
    int t = threadIdx.x, wave = t >> 6, lane = t & 63, lrow = lane & 15, quad = lane >> 4;
    int wm = wave & 1, wn = wave >> 1;
    #pragma unroll
    for (int ni = 0; ni < 4; ++ni) {
        int n_g = nb * 128 + wn * 64 + ni * 16 + lrow;
        float bias = outb[n_g];
        #pragma unroll
        for (int mi = 0; mi < 4; ++mi) {
            #pragma unroll
            for (int r = 0; r < 4; ++r) {
                int m_g = mb * 128 + wm * 64 + mi * 16 + quad * 4 + r;
                out[(size_t)m_g * 1024 + n_g] = (acc[mi][ni][r] + bias) * pv[m_g];
            }
        }
    }
    if (nb == 0 && t < 128) out[OUT_LATENT + mb * 128 + t] = pv[mb * 128 + t];
}

// ---------------------------------------------------------------------------
extern "C" void kernel_launch(void* const* d_in, const int* in_sizes, int n_in,
                              void* d_out, int out_size, void* d_ws, size_t ws_size,
                              hipStream_t stream) {
    const int*   tok = (const int*)d_in[0];
    const int*   msk = (const int*)d_in[1];
    const float* emb = (const float*)d_in[2];
    const float* pq  = (const float*)d_in[3];
    const float* ipw = (const float*)d_in[4];
    const float* ipb = (const float*)d_in[5];
    const float* ow  = (const float*)d_in[6];
    const float* ob  = (const float*)d_in[7];
    float* out = (float*)d_out;
    char* ws = (char*)d_ws;

    float* sb_f  = (float*)(ws + 4096);                    // 32 B
    float* pv_f  = (float*)(ws + 8192);                    // 8 KB
    u16*   qk_b  = (u16*)(ws + 16384);                     // 16 KB
    u16*   wv_b  = (u16*)(ws + 32768);                     // 2 MB
    u16*   ow_b  = (u16*)(ws + 32768 + 2097152);           // 2 MB
    u16*   ctx_b = (u16*)(ws + 32768 + 2 * 2097152);       // 4 MB
    u16*   M_b   = (u16*)(ws + 32768 + 2 * 2097152 + 4194304); // 32 MB

    k_prep<<<dim3(2112), dim3(256), 0, stream>>>(ipw, ipb, pq, ow, wv_b, ow_b, qk_b, sb_f);
    k_attn<<<dim3(2048), dim3(256), 0, stream>>>(tok, msk, emb, qk_b, sb_f, M_b, pv_f);
    k_gemm_ctx<<<dim3(16, 8), dim3(256), 0, stream>>>(M_b, wv_b, ipb, ctx_b);
    k_gemm_out<<<dim3(16, 8), dim3(256), 0, stream>>>(ctx_b, ow_b, ob, pv_f, out);
}